// Round 1
// baseline (382.827 us; speedup 1.0000x reference)
//
#include <hip/hip_runtime.h>

#define NN 1024
#define MM 2048

// Tap set (rotated-frame offsets), shared across all 4 kernel types:
// h: (0,0)(0,1)(0,2)(0,3)  d: (0,0)(1,1)(2,2)(3,3)
// t: (0,0)(2,1)(3,1)(3,2)  b: (0,0)(1,2)(1,3)(2,3)

__global__ __launch_bounds__(256) void hdtb_lut_kernel(
    const int* __restrict__ img,
    const float4* __restrict__ wh,
    const float4* __restrict__ wd,
    const float4* __restrict__ wt,
    const float4* __restrict__ wb,
    float* __restrict__ out)
{
    const int b  = blockIdx.z;
    const int X0 = blockIdx.x * 32;
    const int Y0 = blockIdx.y * 8;
    const int tx = threadIdx.x, ty = threadIdx.y;
    const int X = X0 + tx, Y = Y0 + ty;

    // tile covers rows [Y0-3, Y0+10], cols [X0-3, X0+34]
    __shared__ unsigned char tile[14][40];

    const int* imgb = img + b * (NN * NN);
    int tid = ty * 32 + tx;
    for (int i = tid; i < 14 * 38; i += 256) {
        int r = i / 38, c = i - r * 38;
        int gy = Y0 - 3 + r;
        int gx = X0 - 3 + c;
        gy = gy < 0 ? 0 : (gy > NN - 1 ? NN - 1 : gy);   // clamped halo slots are never read
        gx = gx < 0 ? 0 : (gx > NN - 1 ? NN - 1 : gx);
        tile[r][c] = (unsigned char)imgb[gy * NN + gx];
    }
    __syncthreads();

    // Reflected coordinate arrays, converted to tile-local indices.
    // Ap[t] = refl(Y+t)           (forward rows)
    // Am[t] = N-1 - refl(N-1-Y+t) (backward rows, ~Y-t with reflection)
    // Bp/Bm same for cols.
    int ApL[4], AmL[4], BpL[4], BmL[4];
    #pragma unroll
    for (int t = 0; t < 4; ++t) {
        int ap = Y + t;              ap = ap < NN ? ap : 2 * NN - 2 - ap;
        int am = (NN - 1 - Y) + t;   am = am < NN ? am : 2 * NN - 2 - am;
        am = NN - 1 - am;
        int bp = X + t;              bp = bp < NN ? bp : 2 * NN - 2 - bp;
        int bm = (NN - 1 - X) + t;   bm = bm < NN ? bm : 2 * NN - 2 - bm;
        bm = NN - 1 - bm;
        ApL[t] = ap - (Y0 - 3);
        AmL[t] = am - (Y0 - 3);
        BpL[t] = bp - (X0 - 3);
        BmL[t] = bm - (X0 - 3);
    }

    float acc00 = 0.f, acc01 = 0.f, acc10 = 0.f, acc11 = 0.f;

    // Per rotation r: window v[dy][dx] = tile[RA[i]][CA[j]] with
    //   r=0: RA=Ap CA=Bp (i=dy,j=dx)    r=1: RA=Ap CA=Bm (i=dx,j=dy)
    //   r=2: RA=Am CA=Bm (i=dy,j=dx)    r=3: RA=Am CA=Bp (i=dx,j=dy)
    // Output sub-block permutation per rotation applied in the scatter.

#define LOOKUP_SUMS(RA, CA, SW)                                                   \
    int v00, v01, v02, v03, v11, v22, v33, v21, v31, v32, v12, v13, v23;          \
    if (!(SW)) {                                                                  \
        v00 = tile[RA[0]][CA[0]]; v01 = tile[RA[0]][CA[1]];                       \
        v02 = tile[RA[0]][CA[2]]; v03 = tile[RA[0]][CA[3]];                       \
        v11 = tile[RA[1]][CA[1]]; v22 = tile[RA[2]][CA[2]];                       \
        v33 = tile[RA[3]][CA[3]];                                                 \
        v21 = tile[RA[2]][CA[1]]; v31 = tile[RA[3]][CA[1]];                       \
        v32 = tile[RA[3]][CA[2]];                                                 \
        v12 = tile[RA[1]][CA[2]]; v13 = tile[RA[1]][CA[3]];                       \
        v23 = tile[RA[2]][CA[3]];                                                 \
    } else { /* v[dy][dx] = tile[RA[dx]][CA[dy]] */                               \
        v00 = tile[RA[0]][CA[0]]; v01 = tile[RA[1]][CA[0]];                       \
        v02 = tile[RA[2]][CA[0]]; v03 = tile[RA[3]][CA[0]];                       \
        v11 = tile[RA[1]][CA[1]]; v22 = tile[RA[2]][CA[2]];                       \
        v33 = tile[RA[3]][CA[3]];                                                 \
        v21 = tile[RA[1]][CA[2]]; v31 = tile[RA[1]][CA[3]];                       \
        v32 = tile[RA[2]][CA[3]];                                                 \
        v12 = tile[RA[2]][CA[1]]; v13 = tile[RA[3]][CA[1]];                       \
        v23 = tile[RA[3]][CA[2]];                                                 \
    }                                                                             \
    int ih = ((v00 * 16 + v01) * 16 + v02) * 16 + v03;                            \
    int id = ((v00 * 16 + v11) * 16 + v22) * 16 + v33;                            \
    int it = ((v00 * 16 + v21) * 16 + v31) * 16 + v32;                            \
    int ibk = ((v00 * 16 + v12) * 16 + v13) * 16 + v23;                           \
    float4 q0 = wh[ih], q1 = wd[id], q2 = wt[it], q3 = wb[ibk];                   \
    float s0 = q0.x + q1.x + q2.x + q3.x;                                         \
    float s1 = q0.y + q1.y + q2.y + q3.y;                                         \
    float s2 = q0.z + q1.z + q2.z + q3.z;                                         \
    float s3 = q0.w + q1.w + q2.w + q3.w;

    { // r = 0: acc[p][q] += s[p*2+q]
        LOOKUP_SUMS(ApL, BpL, 0)
        acc00 += s0; acc01 += s1; acc10 += s2; acc11 += s3;
    }
    { // r = 1: acc[q][1-p]
        LOOKUP_SUMS(ApL, BmL, 1)
        acc01 += s0; acc11 += s1; acc00 += s2; acc10 += s3;
    }
    { // r = 2: acc[1-p][1-q]
        LOOKUP_SUMS(AmL, BmL, 0)
        acc11 += s0; acc10 += s1; acc01 += s2; acc00 += s3;
    }
    { // r = 3: acc[1-q][p]
        LOOKUP_SUMS(AmL, BpL, 1)
        acc10 += s0; acc00 += s1; acc11 += s2; acc01 += s3;
    }
#undef LOOKUP_SUMS

    size_t ob = (size_t)b * MM * MM;
    float2 top = make_float2(acc00 * 0.25f, acc01 * 0.25f);
    float2 bot = make_float2(acc10 * 0.25f, acc11 * 0.25f);
    *reinterpret_cast<float2*>(out + ob + (size_t)(2 * Y) * MM + 2 * X) = top;
    *reinterpret_cast<float2*>(out + ob + (size_t)(2 * Y + 1) * MM + 2 * X) = bot;
}

extern "C" void kernel_launch(void* const* d_in, const int* in_sizes, int n_in,
                              void* d_out, int out_size, void* d_ws, size_t ws_size,
                              hipStream_t stream) {
    const int*    img = (const int*)d_in[0];
    const float4* wh  = (const float4*)d_in[1];
    const float4* wd  = (const float4*)d_in[2];
    const float4* wt  = (const float4*)d_in[3];
    const float4* wb  = (const float4*)d_in[4];
    float* out = (float*)d_out;

    dim3 block(32, 8, 1);
    dim3 grid(NN / 32, NN / 8, 4);
    hdtb_lut_kernel<<<grid, block, 0, stream>>>(img, wh, wd, wt, wb, out);
}

// Round 2
// 343.025 us; speedup vs baseline: 1.1160x; 1.1160x over previous
//
#include <hip/hip_runtime.h>
#include <hip/hip_fp16.h>

#define NN 1024
#define MM 2048
#define NROWS 65536   // 16^4 rows per table

// ---------------------------------------------------------------------------
// Pass 1: convert the four f32 LUTs (float4 rows, 1 MiB each) into packed
// fp16 rows (uint2 = 4 x half, 8 B each) in d_ws. Total 2 MiB -> fits in a
// single XCD's 4 MiB L2 alongside streaming traffic.
// ---------------------------------------------------------------------------
__global__ __launch_bounds__(256) void convert_lut_kernel(
    const float4* __restrict__ wh, const float4* __restrict__ wd,
    const float4* __restrict__ wt, const float4* __restrict__ wb,
    uint2* __restrict__ ws)
{
    int i = blockIdx.x * 256 + threadIdx.x;     // 0 .. 4*65536-1
    int t = i >> 16;
    int r = i & (NROWS - 1);
    const float4* src = (t == 0) ? wh : (t == 1) ? wd : (t == 2) ? wt : wb;
    float4 v = src[r];
    __half2 lo = __floats2half2_rn(v.x, v.y);
    __half2 hi = __floats2half2_rn(v.z, v.w);
    uint2 o;
    o.x = *reinterpret_cast<unsigned*>(&lo);
    o.y = *reinterpret_cast<unsigned*>(&hi);
    ws[i] = o;
}

__device__ __forceinline__ float2 h2f2(unsigned u) {
    __half2 h = *reinterpret_cast<__half2*>(&u);
    return __half22float2(h);
}

// ---------------------------------------------------------------------------
// Pass 2: the fused 16-pass LUT upscaler, gathering 8 B fp16 rows.
// Tap set (rotated-frame offsets):
// h: (0,0)(0,1)(0,2)(0,3)  d: (0,0)(1,1)(2,2)(3,3)
// t: (0,0)(2,1)(3,1)(3,2)  b: (0,0)(1,2)(1,3)(2,3)
// ---------------------------------------------------------------------------
__global__ __launch_bounds__(256) void hdtb_lut_kernel(
    const int* __restrict__ img,
    const uint2* __restrict__ wh,
    const uint2* __restrict__ wd,
    const uint2* __restrict__ wt,
    const uint2* __restrict__ wb,
    float* __restrict__ out)
{
    const int b  = blockIdx.z;
    const int X0 = blockIdx.x * 32;
    const int Y0 = blockIdx.y * 8;
    const int tx = threadIdx.x, ty = threadIdx.y;
    const int X = X0 + tx, Y = Y0 + ty;

    // tile covers rows [Y0-3, Y0+10], cols [X0-3, X0+34]
    __shared__ unsigned char tile[14][40];

    const int* imgb = img + b * (NN * NN);
    int tid = ty * 32 + tx;
    for (int i = tid; i < 14 * 38; i += 256) {
        int r = i / 38, c = i - r * 38;
        int gy = Y0 - 3 + r;
        int gx = X0 - 3 + c;
        gy = gy < 0 ? 0 : (gy > NN - 1 ? NN - 1 : gy);   // clamped halo slots are never read
        gx = gx < 0 ? 0 : (gx > NN - 1 ? NN - 1 : gx);
        tile[r][c] = (unsigned char)imgb[gy * NN + gx];
    }
    __syncthreads();

    // Reflected coordinate arrays, tile-local.
    int ApL[4], AmL[4], BpL[4], BmL[4];
    #pragma unroll
    for (int t = 0; t < 4; ++t) {
        int ap = Y + t;              ap = ap < NN ? ap : 2 * NN - 2 - ap;
        int am = (NN - 1 - Y) + t;   am = am < NN ? am : 2 * NN - 2 - am;
        am = NN - 1 - am;
        int bp = X + t;              bp = bp < NN ? bp : 2 * NN - 2 - bp;
        int bm = (NN - 1 - X) + t;   bm = bm < NN ? bm : 2 * NN - 2 - bm;
        bm = NN - 1 - bm;
        ApL[t] = ap - (Y0 - 3);
        AmL[t] = am - (Y0 - 3);
        BpL[t] = bp - (X0 - 3);
        BmL[t] = bm - (X0 - 3);
    }

    float acc00 = 0.f, acc01 = 0.f, acc10 = 0.f, acc11 = 0.f;

    // Per rotation r: window v[dy][dx] = tile[RA[i]][CA[j]] with
    //   r=0: RA=Ap CA=Bp          r=1: RA=Ap CA=Bm (transposed)
    //   r=2: RA=Am CA=Bm          r=3: RA=Am CA=Bp (transposed)
#define LOOKUP_SUMS(RA, CA, SW)                                                   \
    int v00, v01, v02, v03, v11, v22, v33, v21, v31, v32, v12, v13, v23;          \
    if (!(SW)) {                                                                  \
        v00 = tile[RA[0]][CA[0]]; v01 = tile[RA[0]][CA[1]];                       \
        v02 = tile[RA[0]][CA[2]]; v03 = tile[RA[0]][CA[3]];                       \
        v11 = tile[RA[1]][CA[1]]; v22 = tile[RA[2]][CA[2]];                       \
        v33 = tile[RA[3]][CA[3]];                                                 \
        v21 = tile[RA[2]][CA[1]]; v31 = tile[RA[3]][CA[1]];                       \
        v32 = tile[RA[3]][CA[2]];                                                 \
        v12 = tile[RA[1]][CA[2]]; v13 = tile[RA[1]][CA[3]];                       \
        v23 = tile[RA[2]][CA[3]];                                                 \
    } else { /* v[dy][dx] = tile[RA[dx]][CA[dy]] */                               \
        v00 = tile[RA[0]][CA[0]]; v01 = tile[RA[1]][CA[0]];                       \
        v02 = tile[RA[2]][CA[0]]; v03 = tile[RA[3]][CA[0]];                       \
        v11 = tile[RA[1]][CA[1]]; v22 = tile[RA[2]][CA[2]];                       \
        v33 = tile[RA[3]][CA[3]];                                                 \
        v21 = tile[RA[1]][CA[2]]; v31 = tile[RA[1]][CA[3]];                       \
        v32 = tile[RA[2]][CA[3]];                                                 \
        v12 = tile[RA[2]][CA[1]]; v13 = tile[RA[3]][CA[1]];                       \
        v23 = tile[RA[3]][CA[2]];                                                 \
    }                                                                             \
    int ih  = ((v00 * 16 + v01) * 16 + v02) * 16 + v03;                           \
    int id  = ((v00 * 16 + v11) * 16 + v22) * 16 + v33;                           \
    int it  = ((v00 * 16 + v21) * 16 + v31) * 16 + v32;                           \
    int ibk = ((v00 * 16 + v12) * 16 + v13) * 16 + v23;                           \
    uint2 q0 = wh[ih], q1 = wd[id], q2 = wt[it], q3 = wb[ibk];                    \
    float2 x0 = h2f2(q0.x), x1 = h2f2(q1.x), x2 = h2f2(q2.x), x3 = h2f2(q3.x);    \
    float2 y0 = h2f2(q0.y), y1 = h2f2(q1.y), y2 = h2f2(q2.y), y3 = h2f2(q3.y);    \
    float s0 = x0.x + x1.x + x2.x + x3.x;                                         \
    float s1 = x0.y + x1.y + x2.y + x3.y;                                         \
    float s2 = y0.x + y1.x + y2.x + y3.x;                                         \
    float s3 = y0.y + y1.y + y2.y + y3.y;

    { // r = 0: acc[p][q] += s[p*2+q]
        LOOKUP_SUMS(ApL, BpL, 0)
        acc00 += s0; acc01 += s1; acc10 += s2; acc11 += s3;
    }
    { // r = 1: acc[q][1-p]
        LOOKUP_SUMS(ApL, BmL, 1)
        acc01 += s0; acc11 += s1; acc00 += s2; acc10 += s3;
    }
    { // r = 2: acc[1-p][1-q]
        LOOKUP_SUMS(AmL, BmL, 0)
        acc11 += s0; acc10 += s1; acc01 += s2; acc00 += s3;
    }
    { // r = 3: acc[1-q][p]
        LOOKUP_SUMS(AmL, BpL, 1)
        acc10 += s0; acc00 += s1; acc11 += s2; acc01 += s3;
    }
#undef LOOKUP_SUMS

    size_t ob = (size_t)b * MM * MM;
    float2 top = make_float2(acc00 * 0.25f, acc01 * 0.25f);
    float2 bot = make_float2(acc10 * 0.25f, acc11 * 0.25f);
    *reinterpret_cast<float2*>(out + ob + (size_t)(2 * Y) * MM + 2 * X) = top;
    *reinterpret_cast<float2*>(out + ob + (size_t)(2 * Y + 1) * MM + 2 * X) = bot;
}

extern "C" void kernel_launch(void* const* d_in, const int* in_sizes, int n_in,
                              void* d_out, int out_size, void* d_ws, size_t ws_size,
                              hipStream_t stream) {
    const int*    img = (const int*)d_in[0];
    const float4* wh  = (const float4*)d_in[1];
    const float4* wd  = (const float4*)d_in[2];
    const float4* wt  = (const float4*)d_in[3];
    const float4* wb  = (const float4*)d_in[4];
    float* out = (float*)d_out;

    uint2* luth = (uint2*)d_ws;   // 4 tables x 65536 rows x 8 B = 2 MiB

    convert_lut_kernel<<<dim3(4 * NROWS / 256), dim3(256), 0, stream>>>(
        wh, wd, wt, wb, luth);

    dim3 block(32, 8, 1);
    dim3 grid(NN / 32, NN / 8, 4);
    hdtb_lut_kernel<<<grid, block, 0, stream>>>(
        img, luth, luth + NROWS, luth + 2 * NROWS, luth + 3 * NROWS, out);
}